// Round 4
// baseline (576.015 us; speedup 1.0000x reference)
//
#include <hip/hip_runtime.h>

using f16 = _Float16;
using half8  = __attribute__((ext_vector_type(8))) f16;
using half4v = __attribute__((ext_vector_type(4))) f16;
using float4v = __attribute__((ext_vector_type(4))) float;

#define DEV static __device__ __forceinline__

constexpr int N = 2048, DIM = 1024, H = 16, DH = 64, F6 = 6144;
constexpr int LDSH = 136;  // f16 epilogue row stride (halves)

// ---- LDS-staged path (used by the K=1024 GEMMs k_qkv / k_out only) ----
template<int ROWS, int THREADS>
DEV void stage64(const f16* __restrict__ g, int strideHalves, f16* lds, int tid) {
#pragma unroll
  for (int q = 0; q < (ROWS * 8) / THREADS; ++q) {
    const int chunk = q * THREADS + tid;
    const int m = chunk >> 3, c = (chunk & 7) ^ (m & 7);
    const f16* gp = g + (size_t)m * strideHalves + c * 8;
    __builtin_amdgcn_global_load_lds(
        (const __attribute__((address_space(1))) unsigned int*)gp,
        (__attribute__((address_space(3))) unsigned int*)(lds + chunk * 8), 16, 0, 0);
  }
}

DEV half8 rdfrag(const f16* T, int m, int ks, int q) {
  const int c = (ks * 4 + q) ^ (m & 7);
  return *(const half8*)(T + m * 64 + c * 8);
}

DEV void gemm64(const f16* As, const f16* Bs, int wm, int wn, int l, float4v acc[4][4]) {
  const int q = l >> 4, mm = l & 15;
#pragma unroll
  for (int ks = 0; ks < 2; ++ks) {
    half8 af[4], bf[4];
#pragma unroll
    for (int mi = 0; mi < 4; ++mi) af[mi] = rdfrag(As, wm + mm + mi * 16, ks, q);
#pragma unroll
    for (int ni = 0; ni < 4; ++ni) bf[ni] = rdfrag(Bs, wn + mm + ni * 16, ks, q);
#pragma unroll
    for (int mi = 0; mi < 4; ++mi)
#pragma unroll
      for (int ni = 0; ni < 4; ++ni)
        acc[mi][ni] = __builtin_amdgcn_mfma_f32_16x16x32_f16(af[mi], bf[ni], acc[mi][ni], 0, 0, 0);
  }
}

// Read back a ROWSx128 f16 tile from lds (stride LDSH) -> coalesced b128 stores.
template<int ROWS, int THREADS>
DEV void flush(const f16* lds, f16* __restrict__ g, int strideHalves, int tid) {
  __syncthreads();
#pragma unroll
  for (int q = 0; q < ROWS * 16 / THREADS; ++q) {
    const int idx = q * THREADS + tid, row = idx >> 4, c = idx & 15;
    *(half8*)(g + (size_t)row * strideHalves + c * 8) = *(const half8*)(lds + row * LDSH + c * 8);
  }
  __syncthreads();
}

// p in [0,136) -> (ti,tk), tk<=ti, ordered longest-K-first (ti-tk descending).
DEV void decode_pair(int p, int& ti, int& tk) {
  int t = (int)((sqrtf(8.f * p + 1.f) - 1.f) * 0.5f);
  while (t * (t + 1) / 2 > p) --t;
  while ((t + 1) * (t + 2) / 2 <= p) ++t;
  const int i2 = p - t * (t + 1) / 2;
  ti = (15 - t) + i2;
  tk = i2;
}

__global__ __launch_bounds__(256) void k_cast(const float* __restrict__ s, f16* __restrict__ d, int n4) {
  int i = blockIdx.x * 256 + threadIdx.x;
  if (i < n4) {
    float4 v = ((const float4*)s)[i];
    half4v h;
    h[0] = (f16)v.x; h[1] = (f16)v.y; h[2] = (f16)v.z; h[3] = (f16)v.w;
    ((half4v*)d)[i] = h;
  }
}

// qkvs = x @ w_qkv^T; per-head scatter (block-uniform slot t).
__global__ __launch_bounds__(256) void k_qkv(const f16* __restrict__ xh, const f16* __restrict__ wh,
                                             f16* __restrict__ quh, f16* __restrict__ kuh,
                                             f16* __restrict__ vuh, f16* __restrict__ qch,
                                             f16* __restrict__ kch, f16* __restrict__ vcT) {
  __shared__ __align__(16) f16 lds[128 * LDSH];
  f16* As = lds; f16* Bs = lds + 128 * 64;
  const int tid = threadIdx.x, w = tid >> 6, l = tid & 63;
  const int tm = blockIdx.x * 128, tf = blockIdx.y * 128;
  const int wm = (w >> 1) * 64, wn = (w & 1) * 64;
  float4v acc[4][4] = {};
  for (int k0 = 0; k0 < DIM; k0 += 64) {
    stage64<128, 256>(xh + (size_t)tm * DIM + k0, DIM, As, tid);
    stage64<128, 256>(wh + (size_t)tf * DIM + k0, DIM, Bs, tid);
    __syncthreads();
    gemm64(As, Bs, wm, wn, l, acc);
    __syncthreads();
  }
  const int rbase = (l >> 4) * 4, cidx = l & 15;
  const int t = tf >> 10;
  const float sc = (t == 0 || t == 3) ? 0.125f : 1.f;
  if (t == 5) {
#pragma unroll
    for (int mi = 0; mi < 4; ++mi)
#pragma unroll
      for (int ni = 0; ni < 4; ++ni) {
        const int f = tf + wn + ni * 16 + cidx;
        const int h = (f & 1023) >> 6, d = f & 63;
        half4v p;
#pragma unroll
        for (int r = 0; r < 4; ++r) p[r] = (f16)acc[mi][ni][r];
        *(half4v*)(vcT + ((size_t)h * DH + d) * N + (tm + wm + mi * 16 + rbase)) = p;
      }
  } else {
#pragma unroll
    for (int mi = 0; mi < 4; ++mi)
#pragma unroll
      for (int ni = 0; ni < 4; ++ni)
#pragma unroll
        for (int r = 0; r < 4; ++r)
          lds[(wm + mi * 16 + rbase + r) * LDSH + wn + ni * 16 + cidx] = (f16)(acc[mi][ni][r] * sc);
    __syncthreads();
    f16* dst = (t == 0) ? quh : (t == 1) ? kuh : (t == 2) ? vuh : (t == 3) ? qch : kch;
    const int hb = (tf & 1023) >> 6;
#pragma unroll
    for (int q = 0; q < 8; ++q) {
      const int idx = q * 256 + tid, row = idx >> 4, c = idx & 15;
      const int h = hb + (c >> 3), d0 = (c & 7) * 8, n = tm + row;
      *(half8*)(dst + ((size_t)h * N + n) * DH + d0) = *(const half8*)(lds + row * LDSH + c * 8);
    }
  }
}

// Per pair (a<=b): term1 tile = tril(qc.vu^T), sig tile = triu1(sigmoid(qu.ku^T)).
// Register-direct A/B frags (K=64, stride DH) — no LDS staging, no K-loop barriers.
__global__ __launch_bounds__(256) void k_t1sig(const f16* __restrict__ qch, const f16* __restrict__ quh,
                                               const f16* __restrict__ vuh, const f16* __restrict__ kuh,
                                               f16* __restrict__ term1, f16* __restrict__ sigb, int h0) {
  __shared__ __align__(16) f16 lds[128 * LDSH];
  int b, a;
  decode_pair(blockIdx.x, b, a);
  const int hl = blockIdx.y, h = h0 + hl;
  const int tid = threadIdx.x, w = tid >> 6, l = tid & 63;
  const int wm = (w >> 1) * 64, wn = (w & 1) * 64;
  const int q = l >> 4, m = l & 15;
  const int rbase = q * 4, cidx = m;
  const size_t ho = (size_t)h * N * DH;
  const f16* qc = qch + ho; const f16* vu = vuh + ho;
  const f16* qu = quh + ho; const f16* ku = kuh + ho;

  {  // term1 = tril(qc[b] . vu[a]^T)
    float4v acc[4][4] = {};
    half8 af[4][2], bf[4][2];
#pragma unroll
    for (int mi = 0; mi < 4; ++mi)
#pragma unroll
      for (int ks = 0; ks < 2; ++ks) {
        af[mi][ks] = *(const half8*)(qc + (b * 128 + wm + mi * 16 + m) * DH + ks * 32 + q * 8);
        bf[mi][ks] = *(const half8*)(vu + (a * 128 + wn + mi * 16 + m) * DH + ks * 32 + q * 8);
      }
#pragma unroll
    for (int ks = 0; ks < 2; ++ks)
#pragma unroll
      for (int mi = 0; mi < 4; ++mi)
#pragma unroll
        for (int ni = 0; ni < 4; ++ni)
          acc[mi][ni] = __builtin_amdgcn_mfma_f32_16x16x32_f16(af[mi][ks], bf[ni][ks], acc[mi][ni], 0, 0, 0);
#pragma unroll
    for (int mi = 0; mi < 4; ++mi)
#pragma unroll
      for (int ni = 0; ni < 4; ++ni)
#pragma unroll
        for (int r = 0; r < 4; ++r) {
          const int i = b * 128 + wm + mi * 16 + rbase + r;
          const int j = a * 128 + wn + ni * 16 + cidx;
          lds[(wm + mi * 16 + rbase + r) * LDSH + wn + ni * 16 + cidx] = (j <= i) ? (f16)acc[mi][ni][r] : (f16)0.f;
        }
    flush<128, 256>(lds, term1 + (size_t)hl * N * N + (size_t)(b * 128) * N + a * 128, N, tid);
  }
  {  // sig = triu1(sigmoid(qu[a] . ku[b]^T))
    float4v acc[4][4] = {};
    half8 af[4][2], bf[4][2];
#pragma unroll
    for (int mi = 0; mi < 4; ++mi)
#pragma unroll
      for (int ks = 0; ks < 2; ++ks) {
        af[mi][ks] = *(const half8*)(qu + (a * 128 + wm + mi * 16 + m) * DH + ks * 32 + q * 8);
        bf[mi][ks] = *(const half8*)(ku + (b * 128 + wn + mi * 16 + m) * DH + ks * 32 + q * 8);
      }
#pragma unroll
    for (int ks = 0; ks < 2; ++ks)
#pragma unroll
      for (int mi = 0; mi < 4; ++mi)
#pragma unroll
        for (int ni = 0; ni < 4; ++ni)
          acc[mi][ni] = __builtin_amdgcn_mfma_f32_16x16x32_f16(af[mi][ks], bf[ni][ks], acc[mi][ni], 0, 0, 0);
#pragma unroll
    for (int mi = 0; mi < 4; ++mi)
#pragma unroll
      for (int ni = 0; ni < 4; ++ni)
#pragma unroll
        for (int r = 0; r < 4; ++r) {
          const int i = a * 128 + wm + mi * 16 + rbase + r;
          const int j = b * 128 + wn + ni * 16 + cidx;
          const float x = acc[mi][ni][r];
          lds[(wm + mi * 16 + rbase + r) * LDSH + wn + ni * 16 + cidx] =
              (j > i) ? (f16)(1.f / (1.f + __expf(-x))) : (f16)0.f;
        }
    flush<128, 256>(lds, sigb + (size_t)hl * N * N + (size_t)(a * 128) * N + b * 128, N, tid);
  }
}

// scores = qc.kc^T - silu(term1 @ sig^T). 128x128 tiles, register-direct frags,
// zero barriers in the K-loop. silu fused via MFMA C-operand, f16 scores out.
__global__ __launch_bounds__(256) void k_su(const f16* __restrict__ term1, const f16* __restrict__ sigb,
                                            const f16* __restrict__ qch, const f16* __restrict__ kch,
                                            f16* __restrict__ scob, int h0) {
  __shared__ __align__(16) f16 lds[128 * LDSH];
  int ti, tk;
  decode_pair(blockIdx.x, ti, tk);
  const int hl = blockIdx.y;
  const int tid = threadIdx.x, w = tid >> 6, l = tid & 63;
  const int wm = (w >> 1) * 64, wn = (w & 1) * 64;
  const int q = l >> 4, m = l & 15;
  const f16* Tb = term1 + (size_t)hl * N * N;
  const f16* Sb = sigb + (size_t)hl * N * N;
  int arow[4], brow[4];
#pragma unroll
  for (int mi = 0; mi < 4; ++mi) {
    arow[mi] = (ti * 128 + wm + mi * 16 + m) * N + q * 8;
    brow[mi] = (tk * 128 + wn + mi * 16 + m) * N + q * 8;
  }
  float4v acc[4][4] = {};
  const int jend = (ti + 1) * 128;
  for (int j0 = tk * 128; j0 < jend; j0 += 64) {
    half8 af[4][2], bf[4][2];
#pragma unroll
    for (int mi = 0; mi < 4; ++mi)
#pragma unroll
      for (int ks = 0; ks < 2; ++ks) {
        af[mi][ks] = *(const half8*)(Tb + arow[mi] + j0 + ks * 32);
        bf[mi][ks] = *(const half8*)(Sb + brow[mi] + j0 + ks * 32);
      }
#pragma unroll
    for (int ks = 0; ks < 2; ++ks)
#pragma unroll
      for (int mi = 0; mi < 4; ++mi)
#pragma unroll
        for (int ni = 0; ni < 4; ++ni)
          acc[mi][ni] = __builtin_amdgcn_mfma_f32_16x16x32_f16(af[mi][ks], bf[ni][ks], acc[mi][ni], 0, 0, 0);
  }
#pragma unroll
  for (int mi = 0; mi < 4; ++mi)
#pragma unroll
    for (int ni = 0; ni < 4; ++ni)
#pragma unroll
      for (int r = 0; r < 4; ++r) {
        const float x = acc[mi][ni][r];
        acc[mi][ni][r] = -(x / (1.f + __expf(-x)));  // -silu(Su)
      }
  const size_t ho = (size_t)(h0 + hl) * N * DH;
  {  // acc += Sc = qc[ti] . kc[tk]^T
    const f16* qc = qch + ho; const f16* kc = kch + ho;
    half8 af[4][2], bf[4][2];
#pragma unroll
    for (int mi = 0; mi < 4; ++mi)
#pragma unroll
      for (int ks = 0; ks < 2; ++ks) {
        af[mi][ks] = *(const half8*)(qc + (ti * 128 + wm + mi * 16 + m) * DH + ks * 32 + q * 8);
        bf[mi][ks] = *(const half8*)(kc + (tk * 128 + wn + mi * 16 + m) * DH + ks * 32 + q * 8);
      }
#pragma unroll
    for (int ks = 0; ks < 2; ++ks)
#pragma unroll
      for (int mi = 0; mi < 4; ++mi)
#pragma unroll
        for (int ni = 0; ni < 4; ++ni)
          acc[mi][ni] = __builtin_amdgcn_mfma_f32_16x16x32_f16(af[mi][ks], bf[ni][ks], acc[mi][ni], 0, 0, 0);
  }
  const int rbase = q * 4, cidx = m;
#pragma unroll
  for (int mi = 0; mi < 4; ++mi)
#pragma unroll
    for (int ni = 0; ni < 4; ++ni)
#pragma unroll
      for (int r = 0; r < 4; ++r)
        lds[(wm + mi * 16 + rbase + r) * LDSH + wn + ni * 16 + cidx] = (f16)acc[mi][ni][r];
  flush<128, 256>(lds, scob + (size_t)hl * N * N + (size_t)(ti * 128) * N + tk * 128, N, tid);
}

// Fused softmax(scores) @ vc with flash-style online softmax. One block per
// (32-row tile, head); 4 waves split the j-tiles (jt % 4 == wave), merged via LDS.
// Scores read register-direct in A-frag layout; V read from vcT in B-frag layout.
__global__ __launch_bounds__(256) void k_avs(const f16* __restrict__ scob, const f16* __restrict__ vcT,
                                             f16* __restrict__ Oh, int h0) {
  __shared__ float mlds[4][32], llds[4][32];
  __shared__ __align__(16) float olds[32][68];
  const int mt = 63 - blockIdx.x;  // longest-first
  const int hl = blockIdx.y, h = h0 + hl;
  const int tid = threadIdx.x, w = tid >> 6, l = tid & 63;
  const int q = l >> 4, m = l & 15;
  const f16* S = scob + (size_t)hl * N * N + (size_t)(mt * 32) * N;
  const f16* V = vcT + (size_t)h * DH * N;
  int srow[2], vrow[4];
#pragma unroll
  for (int mi = 0; mi < 2; ++mi) srow[mi] = (mi * 16 + m) * N + q * 8;
#pragma unroll
  for (int ni = 0; ni < 4; ++ni) vrow[ni] = (ni * 16 + m) * N + q * 8;
  float4v o[2][4] = {};
  float mrun[2] = {-1e30f, -1e30f}, lrun[2] = {0.f, 0.f};
  const int jtmax = mt >> 1;  // inclusive; diagonal tile == jtmax
  for (int jt = w; jt <= jtmax; jt += 4) {
    const int j0 = jt * 64;
    float alphav[2];
    half8 pf[2][2];
#pragma unroll
    for (int mi = 0; mi < 2; ++mi) {
      half8 sf[2];
#pragma unroll
      for (int ks = 0; ks < 2; ++ks) sf[ks] = *(const half8*)(S + srow[mi] + j0 + ks * 32);
      const int rowg = mt * 32 + mi * 16 + m;
      float vals[16];
      float tmx = -1e30f;
#pragma unroll
      for (int ks = 0; ks < 2; ++ks)
#pragma unroll
        for (int e = 0; e < 8; ++e) {
          const int col = j0 + ks * 32 + q * 8 + e;
          const float x = (jt < jtmax || col <= rowg) ? (float)sf[ks][e] : -1e30f;
          vals[ks * 8 + e] = x;
          tmx = fmaxf(tmx, x);
        }
      tmx = fmaxf(tmx, __shfl_xor(tmx, 16));
      tmx = fmaxf(tmx, __shfl_xor(tmx, 32));
      const float nm = fmaxf(mrun[mi], tmx);
      const float al = __expf(mrun[mi] - nm);
      float ts = 0.f;
#pragma unroll
      for (int ks = 0; ks < 2; ++ks)
#pragma unroll
        for (int e = 0; e < 8; ++e) {
          const float p = __expf(vals[ks * 8 + e] - nm);
          pf[mi][ks][e] = (f16)p;
          ts += p;
        }
      ts += __shfl_xor(ts, 16);
      ts += __shfl_xor(ts, 32);
      lrun[mi] = lrun[mi] * al + ts;
      mrun[mi] = nm;
      alphav[mi] = al;
    }
#pragma unroll
    for (int mi = 0; mi < 2; ++mi)
#pragma unroll
      for (int r = 0; r < 4; ++r) {
        const float a = __shfl(alphav[mi], q * 4 + r);
#pragma unroll
        for (int ni = 0; ni < 4; ++ni) o[mi][ni][r] *= a;
      }
#pragma unroll
    for (int ni = 0; ni < 4; ++ni)
#pragma unroll
      for (int ks = 0; ks < 2; ++ks) {
        half8 vf = *(const half8*)(V + vrow[ni] + j0 + ks * 32);
#pragma unroll
        for (int mi = 0; mi < 2; ++mi)
          o[mi][ni] = __builtin_amdgcn_mfma_f32_16x16x32_f16(pf[mi][ks], vf, o[mi][ni], 0, 0, 0);
      }
  }
  // merge 4 waves
  if (l < 16)
#pragma unroll
    for (int mi = 0; mi < 2; ++mi) {
      mlds[w][mi * 16 + l] = mrun[mi];
      llds[w][mi * 16 + l] = lrun[mi];
    }
  __syncthreads();
#pragma unroll
  for (int mi = 0; mi < 2; ++mi)
#pragma unroll
    for (int r = 0; r < 4; ++r) {
      const int row = mi * 16 + q * 4 + r;
      const float mstar = fmaxf(fmaxf(mlds[0][row], mlds[1][row]), fmaxf(mlds[2][row], mlds[3][row]));
      const float sw = __expf(mlds[w][row] - mstar);
#pragma unroll
      for (int ni = 0; ni < 4; ++ni) o[mi][ni][r] *= sw;
    }
#pragma unroll
  for (int t = 0; t < 4; ++t) {
    if (w == t) {
#pragma unroll
      for (int mi = 0; mi < 2; ++mi)
#pragma unroll
        for (int ni = 0; ni < 4; ++ni)
#pragma unroll
          for (int r = 0; r < 4; ++r) {
            const int row = mi * 16 + q * 4 + r, col = ni * 16 + m;
            if (t == 0) olds[row][col] = o[mi][ni][r];
            else olds[row][col] += o[mi][ni][r];
          }
    }
    __syncthreads();
  }
  // final: per-row denom + coalesced b128 store
  const int row = tid >> 3, c = tid & 7;
  const float mstar = fmaxf(fmaxf(mlds[0][row], mlds[1][row]), fmaxf(mlds[2][row], mlds[3][row]));
  float denom = 0.f;
#pragma unroll
  for (int t = 0; t < 4; ++t) denom += __expf(mlds[t][row] - mstar) * llds[t][row];
  const float inv = 1.f / denom;
  half8 o8;
#pragma unroll
  for (int e = 0; e < 8; ++e) o8[e] = (f16)(olds[row][c * 8 + e] * inv);
  *(half8*)(Oh + (size_t)(mt * 32 + row) * (H * DH) + h * DH + c * 8) = o8;
}

// out = O @ w_out^T, fp32 result.
__global__ __launch_bounds__(256) void k_out(const f16* __restrict__ Oh, const f16* __restrict__ wo,
                                             float* __restrict__ out) {
  __shared__ __align__(16) f16 lds[128 * LDSH];
  f16* As = lds; f16* Bs = lds + 128 * 64;
  const int tid = threadIdx.x, w = tid >> 6, l = tid & 63;
  const int tm = blockIdx.x * 128, tn = blockIdx.y * 128;
  const int wm = (w >> 1) * 64, wn = (w & 1) * 64;
  float4v acc[4][4] = {};
  for (int k0 = 0; k0 < DIM; k0 += 64) {
    stage64<128, 256>(Oh + (size_t)tm * DIM + k0, DIM, As, tid);
    stage64<128, 256>(wo + (size_t)tn * DIM + k0, DIM, Bs, tid);
    __syncthreads();
    gemm64(As, Bs, wm, wn, l, acc);
    __syncthreads();
  }
  const int rbase = (l >> 4) * 4, cidx = l & 15;
#pragma unroll
  for (int mi = 0; mi < 4; ++mi)
#pragma unroll
    for (int ni = 0; ni < 4; ++ni)
#pragma unroll
      for (int r = 0; r < 4; ++r) {
        const int n = tm + wm + mi * 16 + rbase + r;
        const int dmo = tn + wn + ni * 16 + cidx;
        out[(size_t)n * DIM + dmo] = acc[mi][ni][r];
      }
}

extern "C" void kernel_launch(void* const* d_in, const int* in_sizes, int n_in,
                              void* d_out, int out_size, void* d_ws, size_t ws_size,
                              hipStream_t stream) {
  const float* x = (const float*)d_in[0];
  const float* wqkv = (const float*)d_in[1];
  const float* wout = (const float*)d_in[2];
  float* out = (float*)d_out;
  char* ws = (char*)d_ws;

  size_t off = 0;
  auto alloc = [&](size_t b) { size_t o = off; off += (b + 255) & ~(size_t)255; return o; };
  f16* xh  = (f16*)(ws + alloc((size_t)N * DIM * 2));
  f16* wqh = (f16*)(ws + alloc((size_t)F6 * DIM * 2));
  f16* woh = (f16*)(ws + alloc((size_t)DIM * H * DH * 2));
  f16* quh = (f16*)(ws + alloc((size_t)H * N * DH * 2));
  f16* kuh = (f16*)(ws + alloc((size_t)H * N * DH * 2));
  f16* vuh = (f16*)(ws + alloc((size_t)H * N * DH * 2));
  f16* qch = (f16*)(ws + alloc((size_t)H * N * DH * 2));
  f16* kch = (f16*)(ws + alloc((size_t)H * N * DH * 2));
  f16* vcT = (f16*)(ws + alloc((size_t)H * DH * N * 2));
  f16* Oh  = (f16*)(ws + alloc((size_t)N * H * DH * 2));
  const size_t persist = off;

  const size_t per_head = (size_t)N * N * 2 * 3;  // term1 + sig + scob, all f16
  int G = (ws_size > persist + 4096) ? (int)((ws_size - persist - 4096) / per_head) : 1;
  if (G < 1) G = 1;
  if (G > 16) G = 16;
  f16* term1 = (f16*)(ws + alloc((size_t)G * N * N * 2));
  f16* sigb  = (f16*)(ws + alloc((size_t)G * N * N * 2));
  f16* scob  = (f16*)(ws + alloc((size_t)G * N * N * 2));

  k_cast<<<(N * DIM / 4 + 255) / 256, 256, 0, stream>>>(x, xh, N * DIM / 4);
  k_cast<<<(F6 * DIM / 4 + 255) / 256, 256, 0, stream>>>(wqkv, wqh, F6 * DIM / 4);
  k_cast<<<(DIM * H * DH / 4 + 255) / 256, 256, 0, stream>>>(wout, woh, DIM * H * DH / 4);

  k_qkv<<<dim3(N / 128, F6 / 128), 256, 0, stream>>>(xh, wqh, quh, kuh, vuh, qch, kch, vcT);

  for (int h0 = 0; h0 < H; h0 += G) {
    const int Gr = (H - h0 < G) ? (H - h0) : G;
    k_t1sig<<<dim3(136, Gr), 256, 0, stream>>>(qch, quh, vuh, kuh, term1, sigb, h0);
    k_su<<<dim3(136, Gr), 256, 0, stream>>>(term1, sigb, qch, kch, scob, h0);
    k_avs<<<dim3(64, Gr), 256, 0, stream>>>(scob, vcT, Oh, h0);
  }

  k_out<<<dim3(16, 8), 256, 0, stream>>>(Oh, woh, out);
}

// Round 5
// 429.070 us; speedup vs baseline: 1.3425x; 1.3425x over previous
//
#include <hip/hip_runtime.h>

using f16 = _Float16;
using half8  = __attribute__((ext_vector_type(8))) f16;
using half4v = __attribute__((ext_vector_type(4))) f16;
using float4v = __attribute__((ext_vector_type(4))) float;

#define DEV static __device__ __forceinline__

constexpr int N = 2048, DIM = 1024, H = 16, DH = 64, F6 = 6144;
constexpr int LDSH = 136;  // f16 epilogue row stride (halves)

template<int ROWS, int THREADS>
DEV void stage64(const f16* __restrict__ g, int strideHalves, f16* lds, int tid) {
#pragma unroll
  for (int q = 0; q < (ROWS * 8) / THREADS; ++q) {
    const int chunk = q * THREADS + tid;
    const int m = chunk >> 3, c = (chunk & 7) ^ (m & 7);
    const f16* gp = g + (size_t)m * strideHalves + c * 8;
    __builtin_amdgcn_global_load_lds(
        (const __attribute__((address_space(1))) unsigned int*)gp,
        (__attribute__((address_space(3))) unsigned int*)(lds + chunk * 8), 16, 0, 0);
  }
}

DEV half8 rdfrag(const f16* T, int m, int ks, int q) {
  const int c = (ks * 4 + q) ^ (m & 7);
  return *(const half8*)(T + m * 64 + c * 8);
}

DEV void gemm64(const f16* As, const f16* Bs, int wm, int wn, int l, float4v acc[4][4]) {
  const int q = l >> 4, mm = l & 15;
#pragma unroll
  for (int ks = 0; ks < 2; ++ks) {
    half8 af[4], bf[4];
#pragma unroll
    for (int mi = 0; mi < 4; ++mi) af[mi] = rdfrag(As, wm + mm + mi * 16, ks, q);
#pragma unroll
    for (int ni = 0; ni < 4; ++ni) bf[ni] = rdfrag(Bs, wn + mm + ni * 16, ks, q);
#pragma unroll
    for (int mi = 0; mi < 4; ++mi)
#pragma unroll
      for (int ni = 0; ni < 4; ++ni)
        acc[mi][ni] = __builtin_amdgcn_mfma_f32_16x16x32_f16(af[mi], bf[ni], acc[mi][ni], 0, 0, 0);
  }
}

template<int ROWS, int THREADS>
DEV void flush(const f16* lds, f16* __restrict__ g, int strideHalves, int tid) {
  __syncthreads();
#pragma unroll
  for (int q = 0; q < ROWS * 16 / THREADS; ++q) {
    const int idx = q * THREADS + tid, row = idx >> 4, c = idx & 15;
    *(half8*)(g + (size_t)row * strideHalves + c * 8) = *(const half8*)(lds + row * LDSH + c * 8);
  }
  __syncthreads();
}

// p in [0,136) -> (ti,tk), tk<=ti, ordered longest-K-first (ti-tk descending).
DEV void decode_pair(int p, int& ti, int& tk) {
  int t = (int)((sqrtf(8.f * p + 1.f) - 1.f) * 0.5f);
  while (t * (t + 1) / 2 > p) --t;
  while ((t + 1) * (t + 2) / 2 <= p) ++t;
  const int i2 = p - t * (t + 1) / 2;
  ti = (15 - t) + i2;
  tk = i2;
}

__global__ __launch_bounds__(256) void k_cast(const float* __restrict__ s, f16* __restrict__ d, int n4) {
  int i = blockIdx.x * 256 + threadIdx.x;
  if (i < n4) {
    float4 v = ((const float4*)s)[i];
    half4v h;
    h[0] = (f16)v.x; h[1] = (f16)v.y; h[2] = (f16)v.z; h[3] = (f16)v.w;
    ((half4v*)d)[i] = h;
  }
}

// qkvs = x @ w_qkv^T; per-head scatter (block-uniform slot t).
__global__ __launch_bounds__(256) void k_qkv(const f16* __restrict__ xh, const f16* __restrict__ wh,
                                             f16* __restrict__ quh, f16* __restrict__ kuh,
                                             f16* __restrict__ vuh, f16* __restrict__ qch,
                                             f16* __restrict__ kch, f16* __restrict__ vcT) {
  __shared__ __align__(16) f16 lds[128 * LDSH];
  f16* As = lds; f16* Bs = lds + 128 * 64;
  const int tid = threadIdx.x, w = tid >> 6, l = tid & 63;
  const int tm = blockIdx.x * 128, tf = blockIdx.y * 128;
  const int wm = (w >> 1) * 64, wn = (w & 1) * 64;
  float4v acc[4][4] = {};
  for (int k0 = 0; k0 < DIM; k0 += 64) {
    stage64<128, 256>(xh + (size_t)tm * DIM + k0, DIM, As, tid);
    stage64<128, 256>(wh + (size_t)tf * DIM + k0, DIM, Bs, tid);
    __syncthreads();
    gemm64(As, Bs, wm, wn, l, acc);
    __syncthreads();
  }
  const int rbase = (l >> 4) * 4, cidx = l & 15;
  const int t = tf >> 10;
  const float sc = (t == 0 || t == 3) ? 0.125f : 1.f;
  if (t == 5) {
#pragma unroll
    for (int mi = 0; mi < 4; ++mi)
#pragma unroll
      for (int ni = 0; ni < 4; ++ni) {
        const int f = tf + wn + ni * 16 + cidx;
        const int h = (f & 1023) >> 6, d = f & 63;
        half4v p;
#pragma unroll
        for (int r = 0; r < 4; ++r) p[r] = (f16)acc[mi][ni][r];
        *(half4v*)(vcT + ((size_t)h * DH + d) * N + (tm + wm + mi * 16 + rbase)) = p;
      }
  } else {
#pragma unroll
    for (int mi = 0; mi < 4; ++mi)
#pragma unroll
      for (int ni = 0; ni < 4; ++ni)
#pragma unroll
        for (int r = 0; r < 4; ++r)
          lds[(wm + mi * 16 + rbase + r) * LDSH + wn + ni * 16 + cidx] = (f16)(acc[mi][ni][r] * sc);
    __syncthreads();
    f16* dst = (t == 0) ? quh : (t == 1) ? kuh : (t == 2) ? vuh : (t == 3) ? qch : kch;
    const int hb = (tf & 1023) >> 6;
#pragma unroll
    for (int q = 0; q < 8; ++q) {
      const int idx = q * 256 + tid, row = idx >> 4, c = idx & 15;
      const int h = hb + (c >> 3), d0 = (c & 7) * 8, n = tm + row;
      *(half8*)(dst + ((size_t)h * N + n) * DH + d0) = *(const half8*)(lds + row * LDSH + c * 8);
    }
  }
}

// Per pair (a<=b): term1 tile = tril(qc.vu^T), sig tile = triu1(sigmoid(qu.ku^T)).
// Register-direct A/B frags (single K=64 step — no K-loop to pipeline).
__global__ __launch_bounds__(256) void k_t1sig(const f16* __restrict__ qch, const f16* __restrict__ quh,
                                               const f16* __restrict__ vuh, const f16* __restrict__ kuh,
                                               f16* __restrict__ term1, f16* __restrict__ sigb, int h0) {
  __shared__ __align__(16) f16 lds[128 * LDSH];
  int b, a;
  decode_pair(blockIdx.x, b, a);
  const int hl = blockIdx.y, h = h0 + hl;
  const int tid = threadIdx.x, w = tid >> 6, l = tid & 63;
  const int wm = (w >> 1) * 64, wn = (w & 1) * 64;
  const int q = l >> 4, m = l & 15;
  const int rbase = q * 4, cidx = m;
  const size_t ho = (size_t)h * N * DH;
  const f16* qc = qch + ho; const f16* vu = vuh + ho;
  const f16* qu = quh + ho; const f16* ku = kuh + ho;

  {  // term1 = tril(qc[b] . vu[a]^T)
    float4v acc[4][4] = {};
    half8 af[4][2], bf[4][2];
#pragma unroll
    for (int mi = 0; mi < 4; ++mi)
#pragma unroll
      for (int ks = 0; ks < 2; ++ks) {
        af[mi][ks] = *(const half8*)(qc + (b * 128 + wm + mi * 16 + m) * DH + ks * 32 + q * 8);
        bf[mi][ks] = *(const half8*)(vu + (a * 128 + wn + mi * 16 + m) * DH + ks * 32 + q * 8);
      }
#pragma unroll
    for (int ks = 0; ks < 2; ++ks)
#pragma unroll
      for (int mi = 0; mi < 4; ++mi)
#pragma unroll
        for (int ni = 0; ni < 4; ++ni)
          acc[mi][ni] = __builtin_amdgcn_mfma_f32_16x16x32_f16(af[mi][ks], bf[ni][ks], acc[mi][ni], 0, 0, 0);
#pragma unroll
    for (int mi = 0; mi < 4; ++mi)
#pragma unroll
      for (int ni = 0; ni < 4; ++ni)
#pragma unroll
        for (int r = 0; r < 4; ++r) {
          const int i = b * 128 + wm + mi * 16 + rbase + r;
          const int j = a * 128 + wn + ni * 16 + cidx;
          lds[(wm + mi * 16 + rbase + r) * LDSH + wn + ni * 16 + cidx] = (j <= i) ? (f16)acc[mi][ni][r] : (f16)0.f;
        }
    flush<128, 256>(lds, term1 + (size_t)hl * N * N + (size_t)(b * 128) * N + a * 128, N, tid);
  }
  {  // sig = triu1(sigmoid(qu[a] . ku[b]^T))
    float4v acc[4][4] = {};
    half8 af[4][2], bf[4][2];
#pragma unroll
    for (int mi = 0; mi < 4; ++mi)
#pragma unroll
      for (int ks = 0; ks < 2; ++ks) {
        af[mi][ks] = *(const half8*)(qu + (a * 128 + wm + mi * 16 + m) * DH + ks * 32 + q * 8);
        bf[mi][ks] = *(const half8*)(ku + (b * 128 + wn + mi * 16 + m) * DH + ks * 32 + q * 8);
      }
#pragma unroll
    for (int ks = 0; ks < 2; ++ks)
#pragma unroll
      for (int mi = 0; mi < 4; ++mi)
#pragma unroll
        for (int ni = 0; ni < 4; ++ni)
          acc[mi][ni] = __builtin_amdgcn_mfma_f32_16x16x32_f16(af[mi][ks], bf[ni][ks], acc[mi][ni], 0, 0, 0);
#pragma unroll
    for (int mi = 0; mi < 4; ++mi)
#pragma unroll
      for (int ni = 0; ni < 4; ++ni)
#pragma unroll
        for (int r = 0; r < 4; ++r) {
          const int i = a * 128 + wm + mi * 16 + rbase + r;
          const int j = b * 128 + wn + ni * 16 + cidx;
          const float x = acc[mi][ni][r];
          lds[(wm + mi * 16 + rbase + r) * LDSH + wn + ni * 16 + cidx] =
              (j > i) ? (f16)(1.f / (1.f + __expf(-x))) : (f16)0.f;
        }
    flush<128, 256>(lds, sigb + (size_t)hl * N * N + (size_t)(a * 128) * N + b * 128, N, tid);
  }
}

// scores = qc.kc^T - silu(term1 @ sig^T). 64x128 output tiles (pair>>1 + row-half),
// 128-thread blocks, longest-K first, LDS-staged K-loop (reverted: register-direct
// regressed 1.8x — per-wave load latency unhidden at this occupancy), f16 scores out.
__global__ __launch_bounds__(128) void k_su(const f16* __restrict__ term1, const f16* __restrict__ sigb,
                                            const f16* __restrict__ qch, const f16* __restrict__ kch,
                                            f16* __restrict__ scob, int h0) {
  __shared__ __align__(16) f16 lds[64 * 64 + 128 * 64];  // As 8KB + Bs 16KB; epilogue overlays
  f16* As = lds; f16* Bs = lds + 64 * 64;
  int ti, tk;
  decode_pair(blockIdx.x >> 1, ti, tk);
  const int half = blockIdx.x & 1;
  const int hl = blockIdx.y;
  const int tid = threadIdx.x, w = tid >> 6, l = tid & 63;
  const int wn = w * 64;
  const int r0 = ti * 128 + half * 64;
  float4v acc[4][4] = {};
  const f16* Ab = term1 + (size_t)hl * N * N + (size_t)r0 * N;
  const f16* Bb = sigb + (size_t)hl * N * N + (size_t)(tk * 128) * N;
  const int jhi = r0 + 64;
  for (int j0 = tk * 128; j0 < jhi; j0 += 64) {
    stage64<64, 128>(Ab + j0, N, As, tid);
    stage64<128, 128>(Bb + j0, N, Bs, tid);
    __syncthreads();
    gemm64(As, Bs, 0, wn, l, acc);
    __syncthreads();
  }
#pragma unroll
  for (int mi = 0; mi < 4; ++mi)
#pragma unroll
    for (int ni = 0; ni < 4; ++ni)
#pragma unroll
      for (int r = 0; r < 4; ++r) {
        const float x = acc[mi][ni][r];
        acc[mi][ni][r] = -(x / (1.f + __expf(-x)));  // -silu(Su)
      }
  const size_t ho = (size_t)(h0 + hl) * N * DH;
  stage64<64, 128>(qch + ho + (size_t)r0 * DH, DH, As, tid);
  stage64<128, 128>(kch + ho + (size_t)(tk * 128) * DH, DH, Bs, tid);
  __syncthreads();
  gemm64(As, Bs, 0, wn, l, acc);  // acc = Sc - silu(Su)
  __syncthreads();

  const int rbase = (l >> 4) * 4, cidx = l & 15;
#pragma unroll
  for (int mi = 0; mi < 4; ++mi)
#pragma unroll
    for (int ni = 0; ni < 4; ++ni)
#pragma unroll
      for (int r = 0; r < 4; ++r)
        lds[(mi * 16 + rbase + r) * LDSH + wn + ni * 16 + cidx] = (f16)acc[mi][ni][r];
  flush<64, 128>(lds, scob + (size_t)hl * N * N + (size_t)r0 * N + tk * 128, N, tid);
}

// Fused softmax(scores) @ vc with flash-style online softmax. One block per
// (32-row tile, head); 4 waves split the j-tiles (jt % 4 == wave), merged via LDS.
__global__ __launch_bounds__(256) void k_avs(const f16* __restrict__ scob, const f16* __restrict__ vcT,
                                             f16* __restrict__ Oh, int h0) {
  __shared__ float mlds[4][32], llds[4][32];
  __shared__ __align__(16) float olds[32][68];
  const int mt = 63 - blockIdx.x;  // longest-first
  const int hl = blockIdx.y, h = h0 + hl;
  const int tid = threadIdx.x, w = tid >> 6, l = tid & 63;
  const int q = l >> 4, m = l & 15;
  const f16* S = scob + (size_t)hl * N * N + (size_t)(mt * 32) * N;
  const f16* V = vcT + (size_t)h * DH * N;
  int srow[2], vrow[4];
#pragma unroll
  for (int mi = 0; mi < 2; ++mi) srow[mi] = (mi * 16 + m) * N + q * 8;
#pragma unroll
  for (int ni = 0; ni < 4; ++ni) vrow[ni] = (ni * 16 + m) * N + q * 8;
  float4v o[2][4] = {};
  float mrun[2] = {-1e30f, -1e30f}, lrun[2] = {0.f, 0.f};
  const int jtmax = mt >> 1;  // inclusive; diagonal tile == jtmax
  for (int jt = w; jt <= jtmax; jt += 4) {
    const int j0 = jt * 64;
    float alphav[2];
    half8 pf[2][2];
#pragma unroll
    for (int mi = 0; mi < 2; ++mi) {
      half8 sf[2];
#pragma unroll
      for (int ks = 0; ks < 2; ++ks) sf[ks] = *(const half8*)(S + srow[mi] + j0 + ks * 32);
      const int rowg = mt * 32 + mi * 16 + m;
      float vals[16];
      float tmx = -1e30f;
#pragma unroll
      for (int ks = 0; ks < 2; ++ks)
#pragma unroll
        for (int e = 0; e < 8; ++e) {
          const int col = j0 + ks * 32 + q * 8 + e;
          const float x = (jt < jtmax || col <= rowg) ? (float)sf[ks][e] : -1e30f;
          vals[ks * 8 + e] = x;
          tmx = fmaxf(tmx, x);
        }
      tmx = fmaxf(tmx, __shfl_xor(tmx, 16));
      tmx = fmaxf(tmx, __shfl_xor(tmx, 32));
      const float nm = fmaxf(mrun[mi], tmx);
      const float al = __expf(mrun[mi] - nm);
      float ts = 0.f;
#pragma unroll
      for (int ks = 0; ks < 2; ++ks)
#pragma unroll
        for (int e = 0; e < 8; ++e) {
          const float p = __expf(vals[ks * 8 + e] - nm);
          pf[mi][ks][e] = (f16)p;
          ts += p;
        }
      ts += __shfl_xor(ts, 16);
      ts += __shfl_xor(ts, 32);
      lrun[mi] = lrun[mi] * al + ts;
      mrun[mi] = nm;
      alphav[mi] = al;
    }
#pragma unroll
    for (int mi = 0; mi < 2; ++mi)
#pragma unroll
      for (int r = 0; r < 4; ++r) {
        const float a = __shfl(alphav[mi], q * 4 + r);
#pragma unroll
        for (int ni = 0; ni < 4; ++ni) o[mi][ni][r] *= a;
      }
#pragma unroll
    for (int ni = 0; ni < 4; ++ni)
#pragma unroll
      for (int ks = 0; ks < 2; ++ks) {
        half8 vf = *(const half8*)(V + vrow[ni] + j0 + ks * 32);
#pragma unroll
        for (int mi = 0; mi < 2; ++mi)
          o[mi][ni] = __builtin_amdgcn_mfma_f32_16x16x32_f16(pf[mi][ks], vf, o[mi][ni], 0, 0, 0);
      }
  }
  // merge 4 waves
  if (l < 16)
#pragma unroll
    for (int mi = 0; mi < 2; ++mi) {
      mlds[w][mi * 16 + l] = mrun[mi];
      llds[w][mi * 16 + l] = lrun[mi];
    }
  __syncthreads();
#pragma unroll
  for (int mi = 0; mi < 2; ++mi)
#pragma unroll
    for (int r = 0; r < 4; ++r) {
      const int row = mi * 16 + q * 4 + r;
      const float mstar = fmaxf(fmaxf(mlds[0][row], mlds[1][row]), fmaxf(mlds[2][row], mlds[3][row]));
      const float sw = __expf(mlds[w][row] - mstar);
#pragma unroll
      for (int ni = 0; ni < 4; ++ni) o[mi][ni][r] *= sw;
    }
#pragma unroll
  for (int t = 0; t < 4; ++t) {
    if (w == t) {
#pragma unroll
      for (int mi = 0; mi < 2; ++mi)
#pragma unroll
        for (int ni = 0; ni < 4; ++ni)
#pragma unroll
          for (int r = 0; r < 4; ++r) {
            const int row = mi * 16 + q * 4 + r, col = ni * 16 + m;
            if (t == 0) olds[row][col] = o[mi][ni][r];
            else olds[row][col] += o[mi][ni][r];
          }
    }
    __syncthreads();
  }
  const int row = tid >> 3, c = tid & 7;
  const float mstar = fmaxf(fmaxf(mlds[0][row], mlds[1][row]), fmaxf(mlds[2][row], mlds[3][row]));
  float denom = 0.f;
#pragma unroll
  for (int t = 0; t < 4; ++t) denom += __expf(mlds[t][row] - mstar) * llds[t][row];
  const float inv = 1.f / denom;
  half8 o8;
#pragma unroll
  for (int e = 0; e < 8; ++e) o8[e] = (f16)(olds[row][c * 8 + e] * inv);
  *(half8*)(Oh + (size_t)(mt * 32 + row) * (H * DH) + h * DH + c * 8) = o8;
}

// out = O @ w_out^T, fp32 result.
__global__ __launch_bounds__(256) void k_out(const f16* __restrict__ Oh, const f16* __restrict__ wo,
                                             float* __restrict__ out) {
  __shared__ __align__(16) f16 lds[128 * LDSH];
  f16* As = lds; f16* Bs = lds + 128 * 64;
  const int tid = threadIdx.x, w = tid >> 6, l = tid & 63;
  const int tm = blockIdx.x * 128, tn = blockIdx.y * 128;
  const int wm = (w >> 1) * 64, wn = (w & 1) * 64;
  float4v acc[4][4] = {};
  for (int k0 = 0; k0 < DIM; k0 += 64) {
    stage64<128, 256>(Oh + (size_t)tm * DIM + k0, DIM, As, tid);
    stage64<128, 256>(wo + (size_t)tn * DIM + k0, DIM, Bs, tid);
    __syncthreads();
    gemm64(As, Bs, wm, wn, l, acc);
    __syncthreads();
  }
  const int rbase = (l >> 4) * 4, cidx = l & 15;
#pragma unroll
  for (int mi = 0; mi < 4; ++mi)
#pragma unroll
    for (int ni = 0; ni < 4; ++ni)
#pragma unroll
      for (int r = 0; r < 4; ++r) {
        const int n = tm + wm + mi * 16 + rbase + r;
        const int dmo = tn + wn + ni * 16 + cidx;
        out[(size_t)n * DIM + dmo] = acc[mi][ni][r];
      }
}

extern "C" void kernel_launch(void* const* d_in, const int* in_sizes, int n_in,
                              void* d_out, int out_size, void* d_ws, size_t ws_size,
                              hipStream_t stream) {
  const float* x = (const float*)d_in[0];
  const float* wqkv = (const float*)d_in[1];
  const float* wout = (const float*)d_in[2];
  float* out = (float*)d_out;
  char* ws = (char*)d_ws;

  size_t off = 0;
  auto alloc = [&](size_t b) { size_t o = off; off += (b + 255) & ~(size_t)255; return o; };
  f16* xh  = (f16*)(ws + alloc((size_t)N * DIM * 2));
  f16* wqh = (f16*)(ws + alloc((size_t)F6 * DIM * 2));
  f16* woh = (f16*)(ws + alloc((size_t)DIM * H * DH * 2));
  f16* quh = (f16*)(ws + alloc((size_t)H * N * DH * 2));
  f16* kuh = (f16*)(ws + alloc((size_t)H * N * DH * 2));
  f16* vuh = (f16*)(ws + alloc((size_t)H * N * DH * 2));
  f16* qch = (f16*)(ws + alloc((size_t)H * N * DH * 2));
  f16* kch = (f16*)(ws + alloc((size_t)H * N * DH * 2));
  f16* vcT = (f16*)(ws + alloc((size_t)H * DH * N * 2));
  f16* Oh  = (f16*)(ws + alloc((size_t)N * H * DH * 2));
  const size_t persist = off;

  const size_t per_head = (size_t)N * N * 2 * 3;  // term1 + sig + scob, all f16
  int G = (ws_size > persist + 4096) ? (int)((ws_size - persist - 4096) / per_head) : 1;
  if (G < 1) G = 1;
  if (G > 16) G = 16;
  f16* term1 = (f16*)(ws + alloc((size_t)G * N * N * 2));
  f16* sigb  = (f16*)(ws + alloc((size_t)G * N * N * 2));
  f16* scob  = (f16*)(ws + alloc((size_t)G * N * N * 2));

  k_cast<<<(N * DIM / 4 + 255) / 256, 256, 0, stream>>>(x, xh, N * DIM / 4);
  k_cast<<<(F6 * DIM / 4 + 255) / 256, 256, 0, stream>>>(wqkv, wqh, F6 * DIM / 4);
  k_cast<<<(DIM * H * DH / 4 + 255) / 256, 256, 0, stream>>>(wout, woh, DIM * H * DH / 4);

  k_qkv<<<dim3(N / 128, F6 / 128), 256, 0, stream>>>(xh, wqh, quh, kuh, vuh, qch, kch, vcT);

  for (int h0 = 0; h0 < H; h0 += G) {
    const int Gr = (H - h0 < G) ? (H - h0) : G;
    k_t1sig<<<dim3(136, Gr), 256, 0, stream>>>(qch, quh, vuh, kuh, term1, sigb, h0);
    k_su<<<dim3(272, Gr), 128, 0, stream>>>(term1, sigb, qch, kch, scob, h0);
    k_avs<<<dim3(64, Gr), 256, 0, stream>>>(scob, vcT, Oh, h0);
  }

  k_out<<<dim3(16, 8), 256, 0, stream>>>(Oh, woh, out);
}

// Round 6
// 404.545 us; speedup vs baseline: 1.4239x; 1.0606x over previous
//
#include <hip/hip_runtime.h>

using f16 = _Float16;
using half8  = __attribute__((ext_vector_type(8))) f16;
using half4v = __attribute__((ext_vector_type(4))) f16;
using float4v = __attribute__((ext_vector_type(4))) float;

#define DEV static __device__ __forceinline__

constexpr int N = 2048, DIM = 1024, H = 16, DH = 64, F6 = 6144;
constexpr int LDSH = 136;       // f16 epilogue row stride (halves)
constexpr int TS = 128 * 128;   // packed tile elements
constexpr int NTILES = 136;     // triangular 128x128 tiles per head

DEV int PL(int i, int k) { return i * (i + 1) / 2 + k; }                  // lower, k<=i
DEV int PU(int a, int b) { return a * 16 - a * (a - 1) / 2 + (b - a); }   // upper, a<=b

template<int ROWS, int THREADS>
DEV void stage64(const f16* __restrict__ g, int strideHalves, f16* lds, int tid) {
#pragma unroll
  for (int q = 0; q < (ROWS * 8) / THREADS; ++q) {
    const int chunk = q * THREADS + tid;
    const int m = chunk >> 3, c = (chunk & 7) ^ (m & 7);
    const f16* gp = g + (size_t)m * strideHalves + c * 8;
    __builtin_amdgcn_global_load_lds(
        (const __attribute__((address_space(1))) unsigned int*)gp,
        (__attribute__((address_space(3))) unsigned int*)(lds + chunk * 8), 16, 0, 0);
  }
}

DEV half8 rdfrag(const f16* T, int m, int ks, int q) {
  const int c = (ks * 4 + q) ^ (m & 7);
  return *(const half8*)(T + m * 64 + c * 8);
}

DEV void gemm64(const f16* As, const f16* Bs, int wm, int wn, int l, float4v acc[4][4]) {
  const int q = l >> 4, mm = l & 15;
#pragma unroll
  for (int ks = 0; ks < 2; ++ks) {
    half8 af[4], bf[4];
#pragma unroll
    for (int mi = 0; mi < 4; ++mi) af[mi] = rdfrag(As, wm + mm + mi * 16, ks, q);
#pragma unroll
    for (int ni = 0; ni < 4; ++ni) bf[ni] = rdfrag(Bs, wn + mm + ni * 16, ks, q);
#pragma unroll
    for (int mi = 0; mi < 4; ++mi)
#pragma unroll
      for (int ni = 0; ni < 4; ++ni)
        acc[mi][ni] = __builtin_amdgcn_mfma_f32_16x16x32_f16(af[mi], bf[ni], acc[mi][ni], 0, 0, 0);
  }
}

template<int ROWS, int THREADS>
DEV void flush(const f16* lds, f16* __restrict__ g, int strideHalves, int tid) {
  __syncthreads();
#pragma unroll
  for (int q = 0; q < ROWS * 16 / THREADS; ++q) {
    const int idx = q * THREADS + tid, row = idx >> 4, c = idx & 15;
    *(half8*)(g + (size_t)row * strideHalves + c * 8) = *(const half8*)(lds + row * LDSH + c * 8);
  }
  __syncthreads();
}

// p in [0,136) -> (ti,tk), tk<=ti, ordered longest-K-first (ti-tk descending).
DEV void decode_pair(int p, int& ti, int& tk) {
  int t = (int)((sqrtf(8.f * p + 1.f) - 1.f) * 0.5f);
  while (t * (t + 1) / 2 > p) --t;
  while ((t + 1) * (t + 2) / 2 <= p) ++t;
  const int i2 = p - t * (t + 1) / 2;
  ti = (15 - t) + i2;
  tk = i2;
}

__global__ __launch_bounds__(256) void k_cast(const float* __restrict__ s, f16* __restrict__ d, int n4) {
  int i = blockIdx.x * 256 + threadIdx.x;
  if (i < n4) {
    float4 v = ((const float4*)s)[i];
    half4v h;
    h[0] = (f16)v.x; h[1] = (f16)v.y; h[2] = (f16)v.z; h[3] = (f16)v.w;
    ((half4v*)d)[i] = h;
  }
}

// qkvs = x @ w_qkv^T; per-head scatter (block-uniform slot t).
__global__ __launch_bounds__(256) void k_qkv(const f16* __restrict__ xh, const f16* __restrict__ wh,
                                             f16* __restrict__ quh, f16* __restrict__ kuh,
                                             f16* __restrict__ vuh, f16* __restrict__ qch,
                                             f16* __restrict__ kch, f16* __restrict__ vcT) {
  __shared__ __align__(16) f16 lds[128 * LDSH];
  f16* As = lds; f16* Bs = lds + 128 * 64;
  const int tid = threadIdx.x, w = tid >> 6, l = tid & 63;
  const int tm = blockIdx.x * 128, tf = blockIdx.y * 128;
  const int wm = (w >> 1) * 64, wn = (w & 1) * 64;
  float4v acc[4][4] = {};
  for (int k0 = 0; k0 < DIM; k0 += 64) {
    stage64<128, 256>(xh + (size_t)tm * DIM + k0, DIM, As, tid);
    stage64<128, 256>(wh + (size_t)tf * DIM + k0, DIM, Bs, tid);
    __syncthreads();
    gemm64(As, Bs, wm, wn, l, acc);
    __syncthreads();
  }
  const int rbase = (l >> 4) * 4, cidx = l & 15;
  const int t = tf >> 10;
  const float sc = (t == 0 || t == 3) ? 0.125f : 1.f;
  if (t == 5) {
#pragma unroll
    for (int mi = 0; mi < 4; ++mi)
#pragma unroll
      for (int ni = 0; ni < 4; ++ni) {
        const int f = tf + wn + ni * 16 + cidx;
        const int h = (f & 1023) >> 6, d = f & 63;
        half4v p;
#pragma unroll
        for (int r = 0; r < 4; ++r) p[r] = (f16)acc[mi][ni][r];
        *(half4v*)(vcT + ((size_t)h * DH + d) * N + (tm + wm + mi * 16 + rbase)) = p;
      }
  } else {
#pragma unroll
    for (int mi = 0; mi < 4; ++mi)
#pragma unroll
      for (int ni = 0; ni < 4; ++ni)
#pragma unroll
        for (int r = 0; r < 4; ++r)
          lds[(wm + mi * 16 + rbase + r) * LDSH + wn + ni * 16 + cidx] = (f16)(acc[mi][ni][r] * sc);
    __syncthreads();
    f16* dst = (t == 0) ? quh : (t == 1) ? kuh : (t == 2) ? vuh : (t == 3) ? qch : kch;
    const int hb = (tf & 1023) >> 6;
#pragma unroll
    for (int q = 0; q < 8; ++q) {
      const int idx = q * 256 + tid, row = idx >> 4, c = idx & 15;
      const int h = hb + (c >> 3), d0 = (c & 7) * 8, n = tm + row;
      *(half8*)(dst + ((size_t)h * N + n) * DH + d0) = *(const half8*)(lds + row * LDSH + c * 8);
    }
  }
}

// Per pair (a<=b): term1 tile (i=b,j=a) = tril(qc.vu^T) -> packed PL(b,a);
// sig tile (i=a,j=b) = triu1(sigmoid(qu.ku^T)) -> packed PU(a,b). Tiles are
// contiguous 32KB blobs (stride 128) -> perfectly coalesced flush.
__global__ __launch_bounds__(256) void k_t1sig(const f16* __restrict__ qch, const f16* __restrict__ quh,
                                               const f16* __restrict__ vuh, const f16* __restrict__ kuh,
                                               f16* __restrict__ term1, f16* __restrict__ sigb, int h0) {
  __shared__ __align__(16) f16 lds[128 * LDSH];
  int b, a;
  decode_pair(blockIdx.x, b, a);
  const int hl = blockIdx.y, h = h0 + hl;
  const int tid = threadIdx.x, w = tid >> 6, l = tid & 63;
  const int wm = (w >> 1) * 64, wn = (w & 1) * 64;
  const int q = l >> 4, m = l & 15;
  const int rbase = q * 4, cidx = m;
  const size_t ho = (size_t)h * N * DH;
  const f16* qc = qch + ho; const f16* vu = vuh + ho;
  const f16* qu = quh + ho; const f16* ku = kuh + ho;

  {  // term1 = tril(qc[b] . vu[a]^T)
    float4v acc[4][4] = {};
    half8 af[4][2], bf[4][2];
#pragma unroll
    for (int mi = 0; mi < 4; ++mi)
#pragma unroll
      for (int ks = 0; ks < 2; ++ks) {
        af[mi][ks] = *(const half8*)(qc + (b * 128 + wm + mi * 16 + m) * DH + ks * 32 + q * 8);
        bf[mi][ks] = *(const half8*)(vu + (a * 128 + wn + mi * 16 + m) * DH + ks * 32 + q * 8);
      }
#pragma unroll
    for (int ks = 0; ks < 2; ++ks)
#pragma unroll
      for (int mi = 0; mi < 4; ++mi)
#pragma unroll
        for (int ni = 0; ni < 4; ++ni)
          acc[mi][ni] = __builtin_amdgcn_mfma_f32_16x16x32_f16(af[mi][ks], bf[ni][ks], acc[mi][ni], 0, 0, 0);
#pragma unroll
    for (int mi = 0; mi < 4; ++mi)
#pragma unroll
      for (int ni = 0; ni < 4; ++ni)
#pragma unroll
        for (int r = 0; r < 4; ++r) {
          const int i = b * 128 + wm + mi * 16 + rbase + r;
          const int j = a * 128 + wn + ni * 16 + cidx;
          lds[(wm + mi * 16 + rbase + r) * LDSH + wn + ni * 16 + cidx] = (j <= i) ? (f16)acc[mi][ni][r] : (f16)0.f;
        }
    flush<128, 256>(lds, term1 + ((size_t)hl * NTILES + PL(b, a)) * TS, 128, tid);
  }
  {  // sig = triu1(sigmoid(qu[a] . ku[b]^T))
    float4v acc[4][4] = {};
    half8 af[4][2], bf[4][2];
#pragma unroll
    for (int mi = 0; mi < 4; ++mi)
#pragma unroll
      for (int ks = 0; ks < 2; ++ks) {
        af[mi][ks] = *(const half8*)(qu + (a * 128 + wm + mi * 16 + m) * DH + ks * 32 + q * 8);
        bf[mi][ks] = *(const half8*)(ku + (b * 128 + wn + mi * 16 + m) * DH + ks * 32 + q * 8);
      }
#pragma unroll
    for (int ks = 0; ks < 2; ++ks)
#pragma unroll
      for (int mi = 0; mi < 4; ++mi)
#pragma unroll
        for (int ni = 0; ni < 4; ++ni)
          acc[mi][ni] = __builtin_amdgcn_mfma_f32_16x16x32_f16(af[mi][ks], bf[ni][ks], acc[mi][ni], 0, 0, 0);
#pragma unroll
    for (int mi = 0; mi < 4; ++mi)
#pragma unroll
      for (int ni = 0; ni < 4; ++ni)
#pragma unroll
        for (int r = 0; r < 4; ++r) {
          const int i = a * 128 + wm + mi * 16 + rbase + r;
          const int j = b * 128 + wn + ni * 16 + cidx;
          const float x = acc[mi][ni][r];
          lds[(wm + mi * 16 + rbase + r) * LDSH + wn + ni * 16 + cidx] =
              (j > i) ? (f16)(1.f / (1.f + __expf(-x))) : (f16)0.f;
        }
    flush<128, 256>(lds, sigb + ((size_t)hl * NTILES + PU(a, b)) * TS, 128, tid);
  }
}

// scores = qc.kc^T - silu(term1 @ sig^T). 64x128 output tiles (pair>>1 + row-half),
// 128-thread blocks, longest-K first, LDS-staged K-loop over packed tiles, packed
// f16 scores out. No triangular masking on store: k_avs predicates on k<=i.
__global__ __launch_bounds__(128) void k_su(const f16* __restrict__ term1, const f16* __restrict__ sigb,
                                            const f16* __restrict__ qch, const f16* __restrict__ kch,
                                            f16* __restrict__ scob, int h0) {
  __shared__ __align__(16) f16 lds[64 * 64 + 128 * 64];  // As 8KB + Bs 16KB; epilogue overlays
  f16* As = lds; f16* Bs = lds + 64 * 64;
  int ti, tk;
  decode_pair(blockIdx.x >> 1, ti, tk);
  const int half = blockIdx.x & 1;
  const int hl = blockIdx.y;
  const int tid = threadIdx.x, w = tid >> 6, l = tid & 63;
  const int wn = w * 64;
  const int r0 = ti * 128 + half * 64;
  float4v acc[4][4] = {};
  const f16* Tb = term1 + (size_t)hl * NTILES * TS;
  const f16* Sb = sigb + (size_t)hl * NTILES * TS;
  const int jhi = r0 + 64;
  for (int j0 = tk * 128; j0 < jhi; j0 += 64) {
    const int tj = j0 >> 7, co = j0 & 127;
    stage64<64, 128>(Tb + (size_t)PL(ti, tj) * TS + half * 64 * 128 + co, 128, As, tid);
    stage64<128, 128>(Sb + (size_t)PU(tk, tj) * TS + co, 128, Bs, tid);
    __syncthreads();
    gemm64(As, Bs, 0, wn, l, acc);
    __syncthreads();
  }
#pragma unroll
  for (int mi = 0; mi < 4; ++mi)
#pragma unroll
    for (int ni = 0; ni < 4; ++ni)
#pragma unroll
      for (int r = 0; r < 4; ++r) {
        const float x = acc[mi][ni][r];
        acc[mi][ni][r] = -(x / (1.f + __expf(-x)));  // -silu(Su)
      }
  const size_t ho = (size_t)(h0 + hl) * N * DH;
  stage64<64, 128>(qch + ho + (size_t)r0 * DH, DH, As, tid);
  stage64<128, 128>(kch + ho + (size_t)(tk * 128) * DH, DH, Bs, tid);
  __syncthreads();
  gemm64(As, Bs, 0, wn, l, acc);  // acc = Sc - silu(Su)
  __syncthreads();

  const int rbase = (l >> 4) * 4, cidx = l & 15;
#pragma unroll
  for (int mi = 0; mi < 4; ++mi)
#pragma unroll
    for (int ni = 0; ni < 4; ++ni)
#pragma unroll
      for (int r = 0; r < 4; ++r)
        lds[(mi * 16 + rbase + r) * LDSH + wn + ni * 16 + cidx] = (f16)acc[mi][ni][r];
  flush<64, 128>(lds, scob + ((size_t)hl * NTILES + PL(ti, tk)) * TS + half * 64 * 128, 128, tid);
}

// Fused softmax(scores) @ vc with flash-style online softmax over packed score
// tiles. One block per (32-row tile, head); 4 waves split j-tiles, merged via LDS.
__global__ __launch_bounds__(256) void k_avs(const f16* __restrict__ scob, const f16* __restrict__ vcT,
                                             f16* __restrict__ Oh, int h0) {
  __shared__ float mlds[4][32], llds[4][32];
  __shared__ __align__(16) float olds[32][68];
  const int mt = 63 - blockIdx.x;  // longest-first
  const int hl = blockIdx.y, h = h0 + hl;
  const int tid = threadIdx.x, w = tid >> 6, l = tid & 63;
  const int q = l >> 4, m = l & 15;
  const f16* Sh = scob + (size_t)hl * NTILES * TS;
  const int titile = mt >> 2, irb = (mt & 3) * 32;
  const f16* V = vcT + (size_t)h * DH * N;
  int vrow[4];
#pragma unroll
  for (int ni = 0; ni < 4; ++ni) vrow[ni] = (ni * 16 + m) * N + q * 8;
  float4v o[2][4] = {};
  float mrun[2] = {-1e30f, -1e30f}, lrun[2] = {0.f, 0.f};
  const int jtmax = mt >> 1;  // inclusive; diagonal tile == jtmax
  for (int jt = w; jt <= jtmax; jt += 4) {
    const int j0 = jt * 64;
    const f16* Sbase = Sh + (size_t)PL(titile, jt >> 1) * TS + (jt & 1) * 64;
    float alphav[2];
    half8 pf[2][2];
#pragma unroll
    for (int mi = 0; mi < 2; ++mi) {
      half8 sf[2];
#pragma unroll
      for (int ks = 0; ks < 2; ++ks)
        sf[ks] = *(const half8*)(Sbase + (irb + mi * 16 + m) * 128 + ks * 32 + q * 8);
      const int rowg = mt * 32 + mi * 16 + m;
      float vals[16];
      float tmx = -1e30f;
#pragma unroll
      for (int ks = 0; ks < 2; ++ks)
#pragma unroll
        for (int e = 0; e < 8; ++e) {
          const int col = j0 + ks * 32 + q * 8 + e;
          const float x = (jt < jtmax || col <= rowg) ? (float)sf[ks][e] : -1e30f;
          vals[ks * 8 + e] = x;
          tmx = fmaxf(tmx, x);
        }
      tmx = fmaxf(tmx, __shfl_xor(tmx, 16));
      tmx = fmaxf(tmx, __shfl_xor(tmx, 32));
      const float nm = fmaxf(mrun[mi], tmx);
      const float al = __expf(mrun[mi] - nm);
      float ts = 0.f;
#pragma unroll
      for (int ks = 0; ks < 2; ++ks)
#pragma unroll
        for (int e = 0; e < 8; ++e) {
          const float p = __expf(vals[ks * 8 + e] - nm);
          pf[mi][ks][e] = (f16)p;
          ts += p;
        }
      ts += __shfl_xor(ts, 16);
      ts += __shfl_xor(ts, 32);
      lrun[mi] = lrun[mi] * al + ts;
      mrun[mi] = nm;
      alphav[mi] = al;
    }
#pragma unroll
    for (int mi = 0; mi < 2; ++mi)
#pragma unroll
      for (int r = 0; r < 4; ++r) {
        const float a = __shfl(alphav[mi], q * 4 + r);
#pragma unroll
        for (int ni = 0; ni < 4; ++ni) o[mi][ni][r] *= a;
      }
#pragma unroll
    for (int ni = 0; ni < 4; ++ni)
#pragma unroll
      for (int ks = 0; ks < 2; ++ks) {
        half8 vf = *(const half8*)(V + vrow[ni] + j0 + ks * 32);
#pragma unroll
        for (int mi = 0; mi < 2; ++mi)
          o[mi][ni] = __builtin_amdgcn_mfma_f32_16x16x32_f16(pf[mi][ks], vf, o[mi][ni], 0, 0, 0);
      }
  }
  // merge 4 waves
  if (l < 16)
#pragma unroll
    for (int mi = 0; mi < 2; ++mi) {
      mlds[w][mi * 16 + l] = mrun[mi];
      llds[w][mi * 16 + l] = lrun[mi];
    }
  __syncthreads();
#pragma unroll
  for (int mi = 0; mi < 2; ++mi)
#pragma unroll
    for (int r = 0; r < 4; ++r) {
      const int row = mi * 16 + q * 4 + r;
      const float mstar = fmaxf(fmaxf(mlds[0][row], mlds[1][row]), fmaxf(mlds[2][row], mlds[3][row]));
      const float sw = __expf(mlds[w][row] - mstar);
#pragma unroll
      for (int ni = 0; ni < 4; ++ni) o[mi][ni][r] *= sw;
    }
#pragma unroll
  for (int t = 0; t < 4; ++t) {
    if (w == t) {
#pragma unroll
      for (int mi = 0; mi < 2; ++mi)
#pragma unroll
        for (int ni = 0; ni < 4; ++ni)
#pragma unroll
          for (int r = 0; r < 4; ++r) {
            const int row = mi * 16 + q * 4 + r, col = ni * 16 + m;
            if (t == 0) olds[row][col] = o[mi][ni][r];
            else olds[row][col] += o[mi][ni][r];
          }
    }
    __syncthreads();
  }
  const int row = tid >> 3, c = tid & 7;
  const float mstar = fmaxf(fmaxf(mlds[0][row], mlds[1][row]), fmaxf(mlds[2][row], mlds[3][row]));
  float denom = 0.f;
#pragma unroll
  for (int t = 0; t < 4; ++t) denom += __expf(mlds[t][row] - mstar) * llds[t][row];
  const float inv = 1.f / denom;
  half8 o8;
#pragma unroll
  for (int e = 0; e < 8; ++e) o8[e] = (f16)(olds[row][c * 8 + e] * inv);
  *(half8*)(Oh + (size_t)(mt * 32 + row) * (H * DH) + h * DH + c * 8) = o8;
}

// out = O @ w_out^T, fp32 result.
__global__ __launch_bounds__(256) void k_out(const f16* __restrict__ Oh, const f16* __restrict__ wo,
                                             float* __restrict__ out) {
  __shared__ __align__(16) f16 lds[128 * LDSH];
  f16* As = lds; f16* Bs = lds + 128 * 64;
  const int tid = threadIdx.x, w = tid >> 6, l = tid & 63;
  const int tm = blockIdx.x * 128, tn = blockIdx.y * 128;
  const int wm = (w >> 1) * 64, wn = (w & 1) * 64;
  float4v acc[4][4] = {};
  for (int k0 = 0; k0 < DIM; k0 += 64) {
    stage64<128, 256>(Oh + (size_t)tm * DIM + k0, DIM, As, tid);
    stage64<128, 256>(wo + (size_t)tn * DIM + k0, DIM, Bs, tid);
    __syncthreads();
    gemm64(As, Bs, wm, wn, l, acc);
    __syncthreads();
  }
  const int rbase = (l >> 4) * 4, cidx = l & 15;
#pragma unroll
  for (int mi = 0; mi < 4; ++mi)
#pragma unroll
    for (int ni = 0; ni < 4; ++ni)
#pragma unroll
      for (int r = 0; r < 4; ++r) {
        const int n = tm + wm + mi * 16 + rbase + r;
        const int dmo = tn + wn + ni * 16 + cidx;
        out[(size_t)n * DIM + dmo] = acc[mi][ni][r];
      }
}

extern "C" void kernel_launch(void* const* d_in, const int* in_sizes, int n_in,
                              void* d_out, int out_size, void* d_ws, size_t ws_size,
                              hipStream_t stream) {
  const float* x = (const float*)d_in[0];
  const float* wqkv = (const float*)d_in[1];
  const float* wout = (const float*)d_in[2];
  float* out = (float*)d_out;
  char* ws = (char*)d_ws;

  size_t off = 0;
  auto alloc = [&](size_t b) { size_t o = off; off += (b + 255) & ~(size_t)255; return o; };
  f16* xh  = (f16*)(ws + alloc((size_t)N * DIM * 2));
  f16* wqh = (f16*)(ws + alloc((size_t)F6 * DIM * 2));
  f16* woh = (f16*)(ws + alloc((size_t)DIM * H * DH * 2));
  f16* quh = (f16*)(ws + alloc((size_t)H * N * DH * 2));
  f16* kuh = (f16*)(ws + alloc((size_t)H * N * DH * 2));
  f16* vuh = (f16*)(ws + alloc((size_t)H * N * DH * 2));
  f16* qch = (f16*)(ws + alloc((size_t)H * N * DH * 2));
  f16* kch = (f16*)(ws + alloc((size_t)H * N * DH * 2));
  f16* vcT = (f16*)(ws + alloc((size_t)H * DH * N * 2));
  f16* Oh  = (f16*)(ws + alloc((size_t)N * H * DH * 2));
  const size_t persist = off;

  // packed triangular tiles: 136 x 32KB per head per buffer (term1+sig+scob)
  const size_t per_head = (size_t)NTILES * TS * 2 * 3;
  int G = (ws_size > persist + 4096) ? (int)((ws_size - persist - 4096) / per_head) : 1;
  if (G < 1) G = 1;
  if (G > 16) G = 16;
  {  // normalize so rounds are evenly sized
    const int R = (H + G - 1) / G;
    G = (H + R - 1) / R;
  }
  f16* term1 = (f16*)(ws + alloc((size_t)G * NTILES * TS * 2));
  f16* sigb  = (f16*)(ws + alloc((size_t)G * NTILES * TS * 2));
  f16* scob  = (f16*)(ws + alloc((size_t)G * NTILES * TS * 2));

  k_cast<<<(N * DIM / 4 + 255) / 256, 256, 0, stream>>>(x, xh, N * DIM / 4);
  k_cast<<<(F6 * DIM / 4 + 255) / 256, 256, 0, stream>>>(wqkv, wqh, F6 * DIM / 4);
  k_cast<<<(DIM * H * DH / 4 + 255) / 256, 256, 0, stream>>>(wout, woh, DIM * H * DH / 4);

  k_qkv<<<dim3(N / 128, F6 / 128), 256, 0, stream>>>(xh, wqh, quh, kuh, vuh, qch, kch, vcT);

  for (int h0 = 0; h0 < H; h0 += G) {
    const int Gr = (H - h0 < G) ? (H - h0) : G;
    k_t1sig<<<dim3(136, Gr), 256, 0, stream>>>(qch, quh, vuh, kuh, term1, sigb, h0);
    k_su<<<dim3(272, Gr), 128, 0, stream>>>(term1, sigb, qch, kch, scob, h0);
    k_avs<<<dim3(64, Gr), 256, 0, stream>>>(scob, vcT, Oh, h0);
  }

  k_out<<<dim3(16, 8), 256, 0, stream>>>(Oh, woh, out);
}

// Round 7
// 392.755 us; speedup vs baseline: 1.4666x; 1.0300x over previous
//
#include <hip/hip_runtime.h>

using f16 = _Float16;
using half8  = __attribute__((ext_vector_type(8))) f16;
using half4v = __attribute__((ext_vector_type(4))) f16;
using float4v = __attribute__((ext_vector_type(4))) float;

#define DEV static __device__ __forceinline__

constexpr int N = 2048, DIM = 1024, H = 16, DH = 64, F6 = 6144;
constexpr int LDSH = 136;       // f16 epilogue row stride (halves)
constexpr int TS = 128 * 128;   // packed tile elements
constexpr int NTILES = 136;     // triangular 128x128 tiles per head

DEV int PL(int i, int k) { return i * (i + 1) / 2 + k; }                  // lower, k<=i
DEV int PU(int a, int b) { return a * 16 - a * (a - 1) / 2 + (b - a); }   // upper, a<=b

template<int ROWS, int THREADS>
DEV void stage64(const f16* __restrict__ g, int strideHalves, f16* lds, int tid) {
#pragma unroll
  for (int q = 0; q < (ROWS * 8) / THREADS; ++q) {
    const int chunk = q * THREADS + tid;
    const int m = chunk >> 3, c = (chunk & 7) ^ (m & 7);
    const f16* gp = g + (size_t)m * strideHalves + c * 8;
    __builtin_amdgcn_global_load_lds(
        (const __attribute__((address_space(1))) unsigned int*)gp,
        (__attribute__((address_space(3))) unsigned int*)(lds + chunk * 8), 16, 0, 0);
  }
}

DEV half8 rdfrag(const f16* T, int m, int ks, int q) {
  const int c = (ks * 4 + q) ^ (m & 7);
  return *(const half8*)(T + m * 64 + c * 8);
}

DEV void gemm64(const f16* As, const f16* Bs, int wm, int wn, int l, float4v acc[4][4]) {
  const int q = l >> 4, mm = l & 15;
#pragma unroll
  for (int ks = 0; ks < 2; ++ks) {
    half8 af[4], bf[4];
#pragma unroll
    for (int mi = 0; mi < 4; ++mi) af[mi] = rdfrag(As, wm + mm + mi * 16, ks, q);
#pragma unroll
    for (int ni = 0; ni < 4; ++ni) bf[ni] = rdfrag(Bs, wn + mm + ni * 16, ks, q);
#pragma unroll
    for (int mi = 0; mi < 4; ++mi)
#pragma unroll
      for (int ni = 0; ni < 4; ++ni)
        acc[mi][ni] = __builtin_amdgcn_mfma_f32_16x16x32_f16(af[mi], bf[ni], acc[mi][ni], 0, 0, 0);
  }
}

template<int ROWS, int THREADS>
DEV void flush(const f16* lds, f16* __restrict__ g, int strideHalves, int tid) {
  __syncthreads();
#pragma unroll
  for (int q = 0; q < ROWS * 16 / THREADS; ++q) {
    const int idx = q * THREADS + tid, row = idx >> 4, c = idx & 15;
    *(half8*)(g + (size_t)row * strideHalves + c * 8) = *(const half8*)(lds + row * LDSH + c * 8);
  }
  __syncthreads();
}

// p in [0,136) -> (ti,tk), tk<=ti, ordered longest-K-first (ti-tk descending).
DEV void decode_pair(int p, int& ti, int& tk) {
  int t = (int)((sqrtf(8.f * p + 1.f) - 1.f) * 0.5f);
  while (t * (t + 1) / 2 > p) --t;
  while ((t + 1) * (t + 2) / 2 <= p) ++t;
  const int i2 = p - t * (t + 1) / 2;
  ti = (15 - t) + i2;
  tk = i2;
}

__global__ __launch_bounds__(256) void k_cast(const float* __restrict__ s, f16* __restrict__ d, int n4) {
  int i = blockIdx.x * 256 + threadIdx.x;
  if (i < n4) {
    float4 v = ((const float4*)s)[i];
    half4v h;
    h[0] = (f16)v.x; h[1] = (f16)v.y; h[2] = (f16)v.z; h[3] = (f16)v.w;
    ((half4v*)d)[i] = h;
  }
}

// qkvs = x @ w_qkv^T; per-head scatter (block-uniform slot t).
__global__ __launch_bounds__(256) void k_qkv(const f16* __restrict__ xh, const f16* __restrict__ wh,
                                             f16* __restrict__ quh, f16* __restrict__ kuh,
                                             f16* __restrict__ vuh, f16* __restrict__ qch,
                                             f16* __restrict__ kch, f16* __restrict__ vcT) {
  __shared__ __align__(16) f16 lds[128 * LDSH];
  f16* As = lds; f16* Bs = lds + 128 * 64;
  const int tid = threadIdx.x, w = tid >> 6, l = tid & 63;
  const int tm = blockIdx.x * 128, tf = blockIdx.y * 128;
  const int wm = (w >> 1) * 64, wn = (w & 1) * 64;
  float4v acc[4][4] = {};
  for (int k0 = 0; k0 < DIM; k0 += 64) {
    stage64<128, 256>(xh + (size_t)tm * DIM + k0, DIM, As, tid);
    stage64<128, 256>(wh + (size_t)tf * DIM + k0, DIM, Bs, tid);
    __syncthreads();
    gemm64(As, Bs, wm, wn, l, acc);
    __syncthreads();
  }
  const int rbase = (l >> 4) * 4, cidx = l & 15;
  const int t = tf >> 10;
  const float sc = (t == 0 || t == 3) ? 0.125f : 1.f;
  if (t == 5) {
#pragma unroll
    for (int mi = 0; mi < 4; ++mi)
#pragma unroll
      for (int ni = 0; ni < 4; ++ni) {
        const int f = tf + wn + ni * 16 + cidx;
        const int h = (f & 1023) >> 6, d = f & 63;
        half4v p;
#pragma unroll
        for (int r = 0; r < 4; ++r) p[r] = (f16)acc[mi][ni][r];
        *(half4v*)(vcT + ((size_t)h * DH + d) * N + (tm + wm + mi * 16 + rbase)) = p;
      }
  } else {
#pragma unroll
    for (int mi = 0; mi < 4; ++mi)
#pragma unroll
      for (int ni = 0; ni < 4; ++ni)
#pragma unroll
        for (int r = 0; r < 4; ++r)
          lds[(wm + mi * 16 + rbase + r) * LDSH + wn + ni * 16 + cidx] = (f16)(acc[mi][ni][r] * sc);
    __syncthreads();
    f16* dst = (t == 0) ? quh : (t == 1) ? kuh : (t == 2) ? vuh : (t == 3) ? qch : kch;
    const int hb = (tf & 1023) >> 6;
#pragma unroll
    for (int q = 0; q < 8; ++q) {
      const int idx = q * 256 + tid, row = idx >> 4, c = idx & 15;
      const int h = hb + (c >> 3), d0 = (c & 7) * 8, n = tm + row;
      *(half8*)(dst + ((size_t)h * N + n) * DH + d0) = *(const half8*)(lds + row * LDSH + c * 8);
    }
  }
}

// Per pair (a<=b): term1 tile (i=b,j=a) = tril(qc.vu^T) -> packed PL(b,a);
// sig tile (i=a,j=b) = triu1(sigmoid(qu.ku^T)) -> packed PU(a,b).
__global__ __launch_bounds__(256) void k_t1sig(const f16* __restrict__ qch, const f16* __restrict__ quh,
                                               const f16* __restrict__ vuh, const f16* __restrict__ kuh,
                                               f16* __restrict__ term1, f16* __restrict__ sigb, int h0) {
  __shared__ __align__(16) f16 lds[128 * LDSH];
  int b, a;
  decode_pair(blockIdx.x, b, a);
  const int hl = blockIdx.y, h = h0 + hl;
  const int tid = threadIdx.x, w = tid >> 6, l = tid & 63;
  const int wm = (w >> 1) * 64, wn = (w & 1) * 64;
  const int q = l >> 4, m = l & 15;
  const int rbase = q * 4, cidx = m;
  const size_t ho = (size_t)h * N * DH;
  const f16* qc = qch + ho; const f16* vu = vuh + ho;
  const f16* qu = quh + ho; const f16* ku = kuh + ho;

  {  // term1 = tril(qc[b] . vu[a]^T)
    float4v acc[4][4] = {};
    half8 af[4][2], bf[4][2];
#pragma unroll
    for (int mi = 0; mi < 4; ++mi)
#pragma unroll
      for (int ks = 0; ks < 2; ++ks) {
        af[mi][ks] = *(const half8*)(qc + (b * 128 + wm + mi * 16 + m) * DH + ks * 32 + q * 8);
        bf[mi][ks] = *(const half8*)(vu + (a * 128 + wn + mi * 16 + m) * DH + ks * 32 + q * 8);
      }
#pragma unroll
    for (int ks = 0; ks < 2; ++ks)
#pragma unroll
      for (int mi = 0; mi < 4; ++mi)
#pragma unroll
        for (int ni = 0; ni < 4; ++ni)
          acc[mi][ni] = __builtin_amdgcn_mfma_f32_16x16x32_f16(af[mi][ks], bf[ni][ks], acc[mi][ni], 0, 0, 0);
#pragma unroll
    for (int mi = 0; mi < 4; ++mi)
#pragma unroll
      for (int ni = 0; ni < 4; ++ni)
#pragma unroll
        for (int r = 0; r < 4; ++r) {
          const int i = b * 128 + wm + mi * 16 + rbase + r;
          const int j = a * 128 + wn + ni * 16 + cidx;
          lds[(wm + mi * 16 + rbase + r) * LDSH + wn + ni * 16 + cidx] = (j <= i) ? (f16)acc[mi][ni][r] : (f16)0.f;
        }
    flush<128, 256>(lds, term1 + ((size_t)hl * NTILES + PL(b, a)) * TS, 128, tid);
  }
  {  // sig = triu1(sigmoid(qu[a] . ku[b]^T))
    float4v acc[4][4] = {};
    half8 af[4][2], bf[4][2];
#pragma unroll
    for (int mi = 0; mi < 4; ++mi)
#pragma unroll
      for (int ks = 0; ks < 2; ++ks) {
        af[mi][ks] = *(const half8*)(qu + (a * 128 + wm + mi * 16 + m) * DH + ks * 32 + q * 8);
        bf[mi][ks] = *(const half8*)(ku + (b * 128 + wn + mi * 16 + m) * DH + ks * 32 + q * 8);
      }
#pragma unroll
    for (int ks = 0; ks < 2; ++ks)
#pragma unroll
      for (int mi = 0; mi < 4; ++mi)
#pragma unroll
        for (int ni = 0; ni < 4; ++ni)
          acc[mi][ni] = __builtin_amdgcn_mfma_f32_16x16x32_f16(af[mi][ks], bf[ni][ks], acc[mi][ni], 0, 0, 0);
#pragma unroll
    for (int mi = 0; mi < 4; ++mi)
#pragma unroll
      for (int ni = 0; ni < 4; ++ni)
#pragma unroll
        for (int r = 0; r < 4; ++r) {
          const int i = a * 128 + wm + mi * 16 + rbase + r;
          const int j = b * 128 + wn + ni * 16 + cidx;
          const float x = acc[mi][ni][r];
          lds[(wm + mi * 16 + rbase + r) * LDSH + wn + ni * 16 + cidx] =
              (j > i) ? (f16)(1.f / (1.f + __expf(-x))) : (f16)0.f;
        }
    flush<128, 256>(lds, sigb + ((size_t)hl * NTILES + PU(a, b)) * TS, 128, tid);
  }
}

// scores = qc.kc^T - silu(term1 @ sig^T). 128x128 output tiles, 256 threads
// (measured-best k_su shape: 64x128 half-tiles doubled staging traffic and
// halved per-step MFMA amortization — reverted). Packed tile I/O, longest-K
// first, silu fused via MFMA C-operand, f16 scores out (k_avs masks k<=i).
__global__ __launch_bounds__(256) void k_su(const f16* __restrict__ term1, const f16* __restrict__ sigb,
                                            const f16* __restrict__ qch, const f16* __restrict__ kch,
                                            f16* __restrict__ scob, int h0) {
  __shared__ __align__(16) f16 lds[128 * LDSH];
  f16* As = lds; f16* Bs = lds + 128 * 64;
  int ti, tk;
  decode_pair(blockIdx.x, ti, tk);
  const int hl = blockIdx.y;
  const int tid = threadIdx.x, w = tid >> 6, l = tid & 63;
  const int wm = (w >> 1) * 64, wn = (w & 1) * 64;
  float4v acc[4][4] = {};
  const f16* Tb = term1 + (size_t)hl * NTILES * TS;
  const f16* Sb = sigb + (size_t)hl * NTILES * TS;
  const int jend = (ti + 1) * 128;
  for (int j0 = tk * 128; j0 < jend; j0 += 64) {
    const int tj = j0 >> 7, co = j0 & 127;
    stage64<128, 256>(Tb + (size_t)PL(ti, tj) * TS + co, 128, As, tid);
    stage64<128, 256>(Sb + (size_t)PU(tk, tj) * TS + co, 128, Bs, tid);
    __syncthreads();
    gemm64(As, Bs, wm, wn, l, acc);
    __syncthreads();
  }
#pragma unroll
  for (int mi = 0; mi < 4; ++mi)
#pragma unroll
    for (int ni = 0; ni < 4; ++ni)
#pragma unroll
      for (int r = 0; r < 4; ++r) {
        const float x = acc[mi][ni][r];
        acc[mi][ni][r] = -(x / (1.f + __expf(-x)));  // -silu(Su)
      }
  const size_t ho = (size_t)(h0 + hl) * N * DH;
  stage64<128, 256>(qch + ho + (size_t)(ti * 128) * DH, DH, As, tid);
  stage64<128, 256>(kch + ho + (size_t)(tk * 128) * DH, DH, Bs, tid);
  __syncthreads();
  gemm64(As, Bs, wm, wn, l, acc);  // acc = Sc - silu(Su)
  __syncthreads();

  const int rbase = (l >> 4) * 4, cidx = l & 15;
#pragma unroll
  for (int mi = 0; mi < 4; ++mi)
#pragma unroll
    for (int ni = 0; ni < 4; ++ni)
#pragma unroll
      for (int r = 0; r < 4; ++r)
        lds[(wm + mi * 16 + rbase + r) * LDSH + wn + ni * 16 + cidx] = (f16)acc[mi][ni][r];
  flush<128, 256>(lds, scob + ((size_t)hl * NTILES + PL(ti, tk)) * TS, 128, tid);
}

// Fused softmax(scores) @ vc with flash-style online softmax over packed score
// tiles. One block per (32-row tile, head); 4 waves split j-tiles, merged via LDS.
__global__ __launch_bounds__(256) void k_avs(const f16* __restrict__ scob, const f16* __restrict__ vcT,
                                             f16* __restrict__ Oh, int h0) {
  __shared__ float mlds[4][32], llds[4][32];
  __shared__ __align__(16) float olds[32][68];
  const int mt = 63 - blockIdx.x;  // longest-first
  const int hl = blockIdx.y, h = h0 + hl;
  const int tid = threadIdx.x, w = tid >> 6, l = tid & 63;
  const int q = l >> 4, m = l & 15;
  const f16* Sh = scob + (size_t)hl * NTILES * TS;
  const int titile = mt >> 2, irb = (mt & 3) * 32;
  const f16* V = vcT + (size_t)h * DH * N;
  int vrow[4];
#pragma unroll
  for (int ni = 0; ni < 4; ++ni) vrow[ni] = (ni * 16 + m) * N + q * 8;
  float4v o[2][4] = {};
  float mrun[2] = {-1e30f, -1e30f}, lrun[2] = {0.f, 0.f};
  const int jtmax = mt >> 1;  // inclusive; diagonal tile == jtmax
  for (int jt = w; jt <= jtmax; jt += 4) {
    const int j0 = jt * 64;
    const f16* Sbase = Sh + (size_t)PL(titile, jt >> 1) * TS + (jt & 1) * 64;
    float alphav[2];
    half8 pf[2][2];
#pragma unroll
    for (int mi = 0; mi < 2; ++mi) {
      half8 sf[2];
#pragma unroll
      for (int ks = 0; ks < 2; ++ks)
        sf[ks] = *(const half8*)(Sbase + (irb + mi * 16 + m) * 128 + ks * 32 + q * 8);
      const int rowg = mt * 32 + mi * 16 + m;
      float vals[16];
      float tmx = -1e30f;
#pragma unroll
      for (int ks = 0; ks < 2; ++ks)
#pragma unroll
        for (int e = 0; e < 8; ++e) {
          const int col = j0 + ks * 32 + q * 8 + e;
          const float x = (jt < jtmax || col <= rowg) ? (float)sf[ks][e] : -1e30f;
          vals[ks * 8 + e] = x;
          tmx = fmaxf(tmx, x);
        }
      tmx = fmaxf(tmx, __shfl_xor(tmx, 16));
      tmx = fmaxf(tmx, __shfl_xor(tmx, 32));
      const float nm = fmaxf(mrun[mi], tmx);
      const float al = __expf(mrun[mi] - nm);
      float ts = 0.f;
#pragma unroll
      for (int ks = 0; ks < 2; ++ks)
#pragma unroll
        for (int e = 0; e < 8; ++e) {
          const float p = __expf(vals[ks * 8 + e] - nm);
          pf[mi][ks][e] = (f16)p;
          ts += p;
        }
      ts += __shfl_xor(ts, 16);
      ts += __shfl_xor(ts, 32);
      lrun[mi] = lrun[mi] * al + ts;
      mrun[mi] = nm;
      alphav[mi] = al;
    }
#pragma unroll
    for (int mi = 0; mi < 2; ++mi)
#pragma unroll
      for (int r = 0; r < 4; ++r) {
        const float a = __shfl(alphav[mi], q * 4 + r);
#pragma unroll
        for (int ni = 0; ni < 4; ++ni) o[mi][ni][r] *= a;
      }
#pragma unroll
    for (int ni = 0; ni < 4; ++ni)
#pragma unroll
      for (int ks = 0; ks < 2; ++ks) {
        half8 vf = *(const half8*)(V + vrow[ni] + j0 + ks * 32);
#pragma unroll
        for (int mi = 0; mi < 2; ++mi)
          o[mi][ni] = __builtin_amdgcn_mfma_f32_16x16x32_f16(pf[mi][ks], vf, o[mi][ni], 0, 0, 0);
      }
  }
  // merge 4 waves
  if (l < 16)
#pragma unroll
    for (int mi = 0; mi < 2; ++mi) {
      mlds[w][mi * 16 + l] = mrun[mi];
      llds[w][mi * 16 + l] = lrun[mi];
    }
  __syncthreads();
#pragma unroll
  for (int mi = 0; mi < 2; ++mi)
#pragma unroll
    for (int r = 0; r < 4; ++r) {
      const int row = mi * 16 + q * 4 + r;
      const float mstar = fmaxf(fmaxf(mlds[0][row], mlds[1][row]), fmaxf(mlds[2][row], mlds[3][row]));
      const float sw = __expf(mlds[w][row] - mstar);
#pragma unroll
      for (int ni = 0; ni < 4; ++ni) o[mi][ni][r] *= sw;
    }
#pragma unroll
  for (int t = 0; t < 4; ++t) {
    if (w == t) {
#pragma unroll
      for (int mi = 0; mi < 2; ++mi)
#pragma unroll
        for (int ni = 0; ni < 4; ++ni)
#pragma unroll
          for (int r = 0; r < 4; ++r) {
            const int row = mi * 16 + q * 4 + r, col = ni * 16 + m;
            if (t == 0) olds[row][col] = o[mi][ni][r];
            else olds[row][col] += o[mi][ni][r];
          }
    }
    __syncthreads();
  }
  const int row = tid >> 3, c = tid & 7;
  const float mstar = fmaxf(fmaxf(mlds[0][row], mlds[1][row]), fmaxf(mlds[2][row], mlds[3][row]));
  float denom = 0.f;
#pragma unroll
  for (int t = 0; t < 4; ++t) denom += __expf(mlds[t][row] - mstar) * llds[t][row];
  const float inv = 1.f / denom;
  half8 o8;
#pragma unroll
  for (int e = 0; e < 8; ++e) o8[e] = (f16)(olds[row][c * 8 + e] * inv);
  *(half8*)(Oh + (size_t)(mt * 32 + row) * (H * DH) + h * DH + c * 8) = o8;
}

// out = O @ w_out^T, fp32 result.
__global__ __launch_bounds__(256) void k_out(const f16* __restrict__ Oh, const f16* __restrict__ wo,
                                             float* __restrict__ out) {
  __shared__ __align__(16) f16 lds[128 * LDSH];
  f16* As = lds; f16* Bs = lds + 128 * 64;
  const int tid = threadIdx.x, w = tid >> 6, l = tid & 63;
  const int tm = blockIdx.x * 128, tn = blockIdx.y * 128;
  const int wm = (w >> 1) * 64, wn = (w & 1) * 64;
  float4v acc[4][4] = {};
  for (int k0 = 0; k0 < DIM; k0 += 64) {
    stage64<128, 256>(Oh + (size_t)tm * DIM + k0, DIM, As, tid);
    stage64<128, 256>(wo + (size_t)tn * DIM + k0, DIM, Bs, tid);
    __syncthreads();
    gemm64(As, Bs, wm, wn, l, acc);
    __syncthreads();
  }
  const int rbase = (l >> 4) * 4, cidx = l & 15;
#pragma unroll
  for (int mi = 0; mi < 4; ++mi)
#pragma unroll
    for (int ni = 0; ni < 4; ++ni)
#pragma unroll
      for (int r = 0; r < 4; ++r) {
        const int n = tm + wm + mi * 16 + rbase + r;
        const int dmo = tn + wn + ni * 16 + cidx;
        out[(size_t)n * DIM + dmo] = acc[mi][ni][r];
      }
}

extern "C" void kernel_launch(void* const* d_in, const int* in_sizes, int n_in,
                              void* d_out, int out_size, void* d_ws, size_t ws_size,
                              hipStream_t stream) {
  const float* x = (const float*)d_in[0];
  const float* wqkv = (const float*)d_in[1];
  const float* wout = (const float*)d_in[2];
  float* out = (float*)d_out;
  char* ws = (char*)d_ws;

  size_t off = 0;
  auto alloc = [&](size_t b) { size_t o = off; off += (b + 255) & ~(size_t)255; return o; };
  f16* xh  = (f16*)(ws + alloc((size_t)N * DIM * 2));
  f16* wqh = (f16*)(ws + alloc((size_t)F6 * DIM * 2));
  f16* woh = (f16*)(ws + alloc((size_t)DIM * H * DH * 2));
  f16* quh = (f16*)(ws + alloc((size_t)H * N * DH * 2));
  f16* kuh = (f16*)(ws + alloc((size_t)H * N * DH * 2));
  f16* vuh = (f16*)(ws + alloc((size_t)H * N * DH * 2));
  f16* qch = (f16*)(ws + alloc((size_t)H * N * DH * 2));
  f16* kch = (f16*)(ws + alloc((size_t)H * N * DH * 2));
  f16* vcT = (f16*)(ws + alloc((size_t)H * DH * N * 2));
  f16* Oh  = (f16*)(ws + alloc((size_t)N * H * DH * 2));
  const size_t persist = off;

  // packed triangular tiles: 136 x 32KB per head per buffer (term1+sig+scob)
  const size_t per_head = (size_t)NTILES * TS * 2 * 3;
  int G = (ws_size > persist + 4096) ? (int)((ws_size - persist - 4096) / per_head) : 1;
  if (G < 1) G = 1;
  if (G > 16) G = 16;
  {  // normalize so rounds are evenly sized
    const int R = (H + G - 1) / G;
    G = (H + R - 1) / R;
  }
  f16* term1 = (f16*)(ws + alloc((size_t)G * NTILES * TS * 2));
  f16* sigb  = (f16*)(ws + alloc((size_t)G * NTILES * TS * 2));
  f16* scob  = (f16*)(ws + alloc((size_t)G * NTILES * TS * 2));

  k_cast<<<(N * DIM / 4 + 255) / 256, 256, 0, stream>>>(x, xh, N * DIM / 4);
  k_cast<<<(F6 * DIM / 4 + 255) / 256, 256, 0, stream>>>(wqkv, wqh, F6 * DIM / 4);
  k_cast<<<(DIM * H * DH / 4 + 255) / 256, 256, 0, stream>>>(wout, woh, DIM * H * DH / 4);

  k_qkv<<<dim3(N / 128, F6 / 128), 256, 0, stream>>>(xh, wqh, quh, kuh, vuh, qch, kch, vcT);

  for (int h0 = 0; h0 < H; h0 += G) {
    const int Gr = (H - h0 < G) ? (H - h0) : G;
    k_t1sig<<<dim3(136, Gr), 256, 0, stream>>>(qch, quh, vuh, kuh, term1, sigb, h0);
    k_su<<<dim3(136, Gr), 256, 0, stream>>>(term1, sigb, qch, kch, scob, h0);
    k_avs<<<dim3(64, Gr), 256, 0, stream>>>(scob, vcT, Oh, h0);
  }

  k_out<<<dim3(16, 8), 256, 0, stream>>>(Oh, woh, out);
}